// Round 5
// baseline (1145.213 us; speedup 1.0000x reference)
//
#include <hip/hip_runtime.h>

typedef __bf16 bf16_t;
typedef __bf16 bf16x8 __attribute__((ext_vector_type(8)));
typedef __bf16 bf16x4 __attribute__((ext_vector_type(4)));
typedef float  f32x4  __attribute__((ext_vector_type(4)));

#define MODE_GELU   0
#define MODE_GATED  1
#define MODE_RES_F  3
#define MODE_FFN2   4

__device__ __forceinline__ void async16(const void* g, void* l) {
  __builtin_amdgcn_global_load_lds(
      (const __attribute__((address_space(1))) void*)g,
      (__attribute__((address_space(3))) void*)l, 16, 0, 0);
}

// fast transcendental helpers: v_exp_f32 / v_rcp_f32 based, bf16-exact
__device__ __forceinline__ float fast_exp(float x) {
  return __builtin_amdgcn_exp2f(x * 1.44269504088896f);
}
__device__ __forceinline__ float fast_sigmoid(float x) {
  return __builtin_amdgcn_rcpf(1.0f + fast_exp(-x));
}
// gelu via Abramowitz-Stegun 7.1.26 erf approx, |eps| <= 1.5e-7
__device__ __forceinline__ float fast_gelu(float x) {
  float u = fabsf(x) * 0.70710678118f;
  float t = __builtin_amdgcn_rcpf(fmaf(0.3275911f, u, 1.0f));
  float p = t * fmaf(t, fmaf(t, fmaf(t, fmaf(t, 1.061405429f, -1.453152027f),
                                     1.421413741f), -0.284496736f), 0.254829592f);
  float e = __builtin_amdgcn_exp2f(-u * u * 1.44269504088896f);
  float erfu = fmaf(-p, e, 1.0f);
  float s = (x >= 0.f) ? erfu : -erfu;
  return 0.5f * x * (1.0f + s);
}

// ---------------------------------------------------------------------------
// GEMM: C = epilogue(A[M,K](lda) @ B^T[N,K]) ; 128x128 tile, BK=64, 16x16x32
// Epilogue is LDS-staged for coalesced global stores (32x128 chunks, 8-lane
// 512B runs); Xres/mask applied at flush time at coalesced addresses.
// ---------------------------------------------------------------------------
template<int MODE>
__launch_bounds__(256, (MODE == MODE_GATED) ? 2 : 3)
__global__ void gemm_mfma(const bf16_t* __restrict__ A,
                          const bf16_t* __restrict__ B1,
                          const bf16_t* __restrict__ B2,
                          const float*  __restrict__ bias,
                          const float*  __restrict__ Xres,
                          const float*  __restrict__ mask,
                          void* __restrict__ Cptr,
                          int M, int N, int K, int lda, int ldC, int coff)
{
  constexpr bool DUAL = (MODE == MODE_GATED);
  __shared__ __align__(16) char smem[DUAL ? 49152 : 32768];
  bf16_t* sA  = (bf16_t*)smem;
  bf16_t* sB  = sA + 8192;
  bf16_t* sB2 = DUAL ? (sB + 8192) : sA;

  const int tid  = threadIdx.x;
  const int wave = tid >> 6;
  const int lane = tid & 63;
  const int wm = wave & 1;
  const int wn = wave >> 1;
  const long m0 = (long)blockIdx.y * 128;
  const long n0 = (long)blockIdx.x * 128;

  f32x4 zero4 = {0.f, 0.f, 0.f, 0.f};
  f32x4 acc[4][4];
  f32x4 acc2[DUAL ? 4 : 1][DUAL ? 4 : 1];
#pragma unroll
  for (int i = 0; i < 4; i++)
#pragma unroll
    for (int j = 0; j < 4; j++) acc[i][j] = zero4;
  if constexpr (DUAL) {
#pragma unroll
    for (int i = 0; i < 4; i++)
#pragma unroll
      for (int j = 0; j < 4; j++) acc2[i][j] = zero4;
  }

  const int q    = lane >> 4;   // 0..3
  const int c16  = lane & 15;
  const int sr   = lane >> 3;   // 0..7
  const int sg   = lane & 7;
  const int stRow = wave * 8 + sr;   // 0..31

  for (long k0 = 0; k0 < K; k0 += 64) {
#pragma unroll
    for (int i = 0; i < 4; i++) {
      int  r     = i * 32 + stRow;
      int  g     = sg ^ (r & 7);
      long gA    = (long)r * lda + k0 + g * 8;
      long gB    = (long)r * K   + k0 + g * 8;
      int  lbase = i * 2048 + wave * 512;   // elements
      async16(A  + m0 * lda + gA, &sA[lbase]);
      async16(B1 + n0 * K   + gB, &sB[lbase]);
      if constexpr (DUAL) async16(B2 + n0 * K + gB, &sB2[lbase]);
    }
    __syncthreads();
#pragma unroll
    for (int kk = 0; kk < 2; kk++) {
      bf16x8 af[4], bfr[4], b2fr[DUAL ? 4 : 1];
#pragma unroll
      for (int i = 0; i < 4; i++) {
        int r = wm * 64 + i * 16 + c16;
        int g = (kk * 4 + q) ^ (r & 7);
        af[i] = *(const bf16x8*)&sA[r * 64 + g * 8];
      }
#pragma unroll
      for (int j = 0; j < 4; j++) {
        int r = wn * 64 + j * 16 + c16;
        int g = (kk * 4 + q) ^ (r & 7);
        bfr[j] = *(const bf16x8*)&sB[r * 64 + g * 8];
        if constexpr (DUAL) b2fr[j] = *(const bf16x8*)&sB2[r * 64 + g * 8];
      }
#pragma unroll
      for (int i = 0; i < 4; i++)
#pragma unroll
        for (int j = 0; j < 4; j++) {
          acc[i][j] = __builtin_amdgcn_mfma_f32_16x16x32_bf16(af[i], bfr[j], acc[i][j], 0, 0, 0);
          if constexpr (DUAL)
            acc2[i][j] = __builtin_amdgcn_mfma_f32_16x16x32_bf16(af[i], b2fr[j], acc2[i][j], 0, 0, 0);
        }
    }
    __syncthreads();
  }

  // epilogue: LDS-staged coalesced writes.
  // C/D layout: col=lane&15, row=(lane>>4)*4+reg  [m89-verified]
  float (*eL)[132] = (float (*)[132])smem;   // 32 x 132 f32, reuses staging LDS
  const int  flr   = tid >> 3;               // 0..31
  const int  fc    = (tid & 7) << 4;         // 0,16,..,112
  const long gRow0 = m0 + (long)((flr >> 4) << 6) + (flr & 15);
  const long gn    = n0 + fc;
#pragma unroll
  for (int i = 0; i < 4; i++) {
#pragma unroll
    for (int j = 0; j < 4; j++) {
      int  lc = wn * 64 + j * 16 + c16;
      long n  = n0 + lc;
#pragma unroll
      for (int r = 0; r < 4; r++) {
        float v = acc[i][j][r];
        float ov;
        if constexpr (MODE == MODE_GELU) {
          ov = fast_gelu(v + bias[n]);
        } else if constexpr (MODE == MODE_GATED) {
          float z  = v + bias[n];
          float gt = acc2[i][j][r] + bias[N + n];
          ov = z * fast_sigmoid(z) * fast_sigmoid(gt);
        } else {
          ov = v + bias[n];
        }
        eL[wm * 16 + q * 4 + r][lc] = ov;
      }
    }
    __syncthreads();
    long gRow = gRow0 + i * 16;
    if constexpr (MODE == MODE_GELU || MODE == MODE_GATED) {
      bf16_t* dst = (bf16_t*)Cptr + gRow * (long)ldC + gn;
      bf16x8 o0, o1;
#pragma unroll
      for (int u = 0; u < 8; u++) {
        o0[u] = (bf16_t)eL[flr][fc + u];
        o1[u] = (bf16_t)eL[flr][fc + 8 + u];
      }
      *(bf16x8*)dst       = o0;
      *(bf16x8*)(dst + 8) = o1;
    } else {
      float* dst = (float*)Cptr + gRow * (long)ldC + gn;
      const float4* xr = (const float4*)(Xres + gRow * (long)N + gn);
      float mk = (MODE == MODE_FFN2) ? mask[gRow] : 1.0f;
#pragma unroll
      for (int u = 0; u < 4; u++) {
        float4 s4 = *(const float4*)&eL[flr][fc + u * 4];
        float4 x4 = xr[u];
        float4 o4;
        o4.x = (x4.x + s4.x) * mk;
        o4.y = (x4.y + s4.y) * mk;
        o4.z = (x4.z + s4.z) * mk;
        o4.w = (x4.w + s4.w) * mk;
        ((float4*)dst)[u] = o4;
      }
    }
    __syncthreads();
  }
}

// ---------------------------------------------------------------------------
// batched composite-weight GEMM (prep): C[m, coff+n] = A[m,:]@B[n,:], bf16 out
// fixed geometry M=512, N=1024, K=512, lda=1024, ldC=2560; 32 blocks/desc
// ---------------------------------------------------------------------------
struct PrepDesc { const bf16_t* A; const bf16_t* B; bf16_t* C; int coff; };
struct PrepArgs { PrepDesc d[4]; };

__launch_bounds__(256, 3)
__global__ void gemm_prep_all(PrepArgs a) {
  PrepDesc d = a.d[blockIdx.x >> 5];
  const int t = blockIdx.x & 31;
  const long m0 = (long)(t >> 3) * 128;
  const long n0 = (long)(t & 7) * 128;
  const int lda = 1024, K = 512, ldC = 2560;

  __shared__ bf16_t sA[128 * 64];
  __shared__ bf16_t sB[128 * 64];

  const int tid  = threadIdx.x;
  const int wave = tid >> 6;
  const int lane = tid & 63;
  const int wm = wave & 1;
  const int wn = wave >> 1;

  f32x4 zero4 = {0.f, 0.f, 0.f, 0.f};
  f32x4 acc[4][4];
#pragma unroll
  for (int i = 0; i < 4; i++)
#pragma unroll
    for (int j = 0; j < 4; j++) acc[i][j] = zero4;

  const int q    = lane >> 4;
  const int c16  = lane & 15;
  const int sr   = lane >> 3;
  const int sg   = lane & 7;
  const int stRow = wave * 8 + sr;

  for (long k0 = 0; k0 < K; k0 += 64) {
#pragma unroll
    for (int i = 0; i < 4; i++) {
      int  r     = i * 32 + stRow;
      int  g     = sg ^ (r & 7);
      int  lbase = i * 2048 + wave * 512;
      async16(d.A + (m0 + r) * lda + k0 + g * 8, &sA[lbase]);
      async16(d.B + (n0 + r) * K   + k0 + g * 8, &sB[lbase]);
    }
    __syncthreads();
#pragma unroll
    for (int kk = 0; kk < 2; kk++) {
      bf16x8 af[4], bfr[4];
#pragma unroll
      for (int i = 0; i < 4; i++) {
        int r = wm * 64 + i * 16 + c16;
        int g = (kk * 4 + q) ^ (r & 7);
        af[i] = *(const bf16x8*)&sA[r * 64 + g * 8];
      }
#pragma unroll
      for (int j = 0; j < 4; j++) {
        int r = wn * 64 + j * 16 + c16;
        int g = (kk * 4 + q) ^ (r & 7);
        bfr[j] = *(const bf16x8*)&sB[r * 64 + g * 8];
      }
#pragma unroll
      for (int i = 0; i < 4; i++)
#pragma unroll
        for (int j = 0; j < 4; j++)
          acc[i][j] = __builtin_amdgcn_mfma_f32_16x16x32_bf16(af[i], bfr[j], acc[i][j], 0, 0, 0);
    }
    __syncthreads();
  }
#pragma unroll
  for (int i = 0; i < 4; i++)
#pragma unroll
    for (int j = 0; j < 4; j++)
#pragma unroll
      for (int r = 0; r < 4; r++) {
        long m = m0 + wm * 64 + i * 16 + q * 4 + r;
        long n = n0 + wn * 64 + j * 16 + c16;
        d.C[m * ldC + d.coff + n] = (bf16_t)acc[i][j][r];
      }
}

// ---------------------------------------------------------------------------
// transpose/cast all weights, one launch, with FUSED bias-fold accumulation:
// mode 0: f32 src[K, srcLd] cols [srcColOff..+ncols) -> bf16 dst[ncols, K],
//         optional per-row gamma scale; optional accOut[j] += sum_k v[k]*raw
//         (v split va/vb at row 512; atomicAdd, init'd by init_bias)
// mode 1: plain elementwise cast
// ---------------------------------------------------------------------------
struct TransDesc { const float* src; bf16_t* dst; const float* rowScale;
                   const float* accVa; const float* accVb; float* accOut;
                   int K, ncols, srcLd, srcColOff, tileBase, mode; };
struct TransArgs { TransDesc d[24]; int nd; };

__global__ void transpose_all(TransArgs args) {
  __shared__ float tile[32][33];
  __shared__ float red[8][32];
  int bid = blockIdx.x;
  int di = 0;
  while (di + 1 < args.nd && bid >= args.d[di + 1].tileBase) ++di;
  TransDesc d = args.d[di];
  int t = bid - d.tileBase;
  if (d.mode == 1) {
    long idx = (long)t * 1024 + threadIdx.x * 4;
    float4 v = *(const float4*)(d.src + idx);
    bf16x4 o; o[0] = (bf16_t)v.x; o[1] = (bf16_t)v.y; o[2] = (bf16_t)v.z; o[3] = (bf16_t)v.w;
    *(bf16x4*)(d.dst + idx) = o;
    return;
  }
  int tilesX = d.ncols >> 5;
  int ty = t / tilesX, tx = t % tilesX;
  int lx = threadIdx.x & 31, ly = threadIdx.x >> 5;  // 32x8
  int gx = tx * 32 + lx;
  float p = 0.f;
#pragma unroll
  for (int i = 0; i < 32; i += 8) {
    int gy = ty * 32 + ly + i;
    float raw = d.src[(long)gy * d.srcLd + d.srcColOff + gx];
    if (d.accOut) {
      float v = (d.accVb && gy >= 512) ? d.accVb[gy - 512] : d.accVa[gy];
      p += v * raw;
    }
    float sc = d.rowScale ? d.rowScale[gy] : 1.f;
    tile[ly + i][lx] = raw * sc;
  }
  if (d.accOut) red[ly][lx] = p;
  __syncthreads();
  if (d.accOut && ly == 0) {
    float s = 0.f;
#pragma unroll
    for (int r = 0; r < 8; r++) s += red[r][lx];
    atomicAdd(&d.accOut[tx * 32 + lx], s);
  }
  int ox = ty * 32 + lx;  // k
#pragma unroll
  for (int i = 0; i < 32; i += 8) {
    int oy = tx * 32 + ly + i;  // n
    d.dst[(long)oy * d.K + ox] = (bf16_t)tile[lx][ly + i];
  }
}

// init bias buffers with their b0 term (before transpose_all's atomics)
struct CopyDesc { const float* src; float* dst; int base, len; };
struct CopyArgs { CopyDesc d[12]; int nd; };
__global__ void init_bias(CopyArgs a) {
  int i = blockIdx.x * 256 + threadIdx.x;
  int di = 0;
  while (di + 1 < a.nd && i >= a.d[di + 1].base) ++di;
  CopyDesc d = a.d[di];
  int j = i - d.base;
  if (j < d.len) d.dst[j] = d.src[j];
}

// Bcomp cols 2048..2559: (Mt+Mb)^T[n,k] = merget[n,k] + merget[n,512+k]
__global__ void build_mtmb(const bf16_t* __restrict__ mt0, bf16_t* __restrict__ bc0,
                           const bf16_t* __restrict__ mt1, bf16_t* __restrict__ bc1) {
  int idx = blockIdx.x * 256 + threadIdx.x;   // 2 * 512 * 512
  int l = idx >> 18;
  int r = idx & 262143;
  int n = r >> 9, k = r & 511;
  const bf16_t* mt = l ? mt1 : mt0;
  bf16_t* bc = l ? bc1 : bc0;
  float v = (float)mt[n * 1024 + k] + (float)mt[n * 1024 + 512 + k];
  bc[(long)n * 2560 + 2048 + k] = (bf16_t)v;
}

// ---------------------------------------------------------------------------
// centroids: one wave per (b,k) row of attn_maps (4096 elems)
// ---------------------------------------------------------------------------
__global__ void centroid_kernel(const float* __restrict__ attn,
                                float* __restrict__ cent,
                                float* __restrict__ outCent) {
  int wave = threadIdx.x >> 6, lane = threadIdx.x & 63;
  long row = (long)blockIdx.x * 4 + wave;
  const float4* ap = (const float4*)(attn + row * 4096);
  float s = 0.f, sx = 0.f, sy = 0.f;
#pragma unroll 4
  for (int t = 0; t < 16; t++) {
    float4 v = ap[t * 64 + lane];
    int n0 = (t * 64 + lane) * 4;
    float col = (float)(n0 & 63);
    float ry  = (float)(n0 >> 6);
    float rs = v.x + v.y + v.z + v.w;
    s  += rs;
    sx += v.x * col + v.y * (col + 1.f) + v.z * (col + 2.f) + v.w * (col + 3.f);
    sy += rs * ry;
  }
#pragma unroll
  for (int o = 32; o; o >>= 1) {
    s += __shfl_down(s, o); sx += __shfl_down(sx, o); sy += __shfl_down(sy, o);
  }
  if (lane == 0) {
    float denom = s + 1e-8f;
    float cx = (sx * (1.f / 63.f)) / denom;
    float cy = (sy * (1.f / 63.f)) / denom;
    cent[row * 2] = cx;     cent[row * 2 + 1] = cy;
    outCent[row * 2] = cx;  outCent[row * 2 + 1] = cy;
  }
}

// ---------------------------------------------------------------------------
// positional encoding rows: enc[row, 256] bf16
// ---------------------------------------------------------------------------
__global__ void enc_kernel(const float* __restrict__ cent, bf16_t* __restrict__ enc) {
  int tid = blockIdx.x * 256 + threadIdx.x;
  int row = tid >> 5, j = tid & 31;
  float cx = cent[row * 2], cy = cent[row * 2 + 1];
  float freq = expf(-(float)j * 0.28782313662425572f);  // 10000^(-j/32)
  float fx = cx * freq * 3.14159f;
  float fy = cy * freq * 3.14159f;
  float fc = 0.1f * freq * 3.14159f;
  bf16_t* e = enc + (long)row * 256;
  float sc = sinf(fc), cc = cosf(fc);
  e[j]        = (bf16_t)sinf(fx);  e[32 + j]  = (bf16_t)cosf(fx);
  e[64 + j]   = (bf16_t)sinf(fy);  e[96 + j]  = (bf16_t)cosf(fy);
  e[128 + j]  = (bf16_t)sc;        e[160 + j] = (bf16_t)cc;
  e[192 + j]  = (bf16_t)sc;        e[224 + j] = (bf16_t)cc;
}

// ---------------------------------------------------------------------------
// plain LN: Xn = (x-mean)*rstd (bf16)  [LN affine folded into weights/bias]
// also writes raw x as bf16 into S cols 2048..2559 (for x@(Mt+Mb) term)
// ---------------------------------------------------------------------------
__global__ void ln_plain_kernel(const float* __restrict__ X,
                                bf16_t* __restrict__ Xn, bf16_t* __restrict__ Sx) {
  int wave = threadIdx.x >> 6, lane = threadIdx.x & 63;
  long row = (long)blockIdx.x * 4 + wave;
  const float4* xp = (const float4*)(X + row * 512);
  float4 v0 = xp[lane], v1 = xp[64 + lane];
  float s  = v0.x + v0.y + v0.z + v0.w + v1.x + v1.y + v1.z + v1.w;
  float s2 = v0.x*v0.x + v0.y*v0.y + v0.z*v0.z + v0.w*v0.w
           + v1.x*v1.x + v1.y*v1.y + v1.z*v1.z + v1.w*v1.w;
#pragma unroll
  for (int o = 32; o; o >>= 1) { s += __shfl_xor(s, o); s2 += __shfl_xor(s2, o); }
  float mean = s * (1.f / 512.f);
  float var  = s2 * (1.f / 512.f) - mean * mean;
  float rstd = rsqrtf(var + 1e-5f);
  float xs[8] = {v0.x, v0.y, v0.z, v0.w, v1.x, v1.y, v1.z, v1.w};
  int   c0 = lane * 4, c1 = 256 + lane * 4;
  bf16x4 pa, pr;
#pragma unroll
  for (int t = 0; t < 4; t++) {
    pa[t] = (bf16_t)((xs[t] - mean) * rstd);
    pr[t] = (bf16_t)xs[t];
  }
  *(bf16x4*)&Xn[row * 512 + c0] = pa;
  *(bf16x4*)&Sx[row * 2560 + c0] = pr;
#pragma unroll
  for (int t = 0; t < 4; t++) {
    pa[t] = (bf16_t)((xs[4 + t] - mean) * rstd);
    pr[t] = (bf16_t)xs[4 + t];
  }
  *(bf16x4*)&Xn[row * 512 + c1] = pa;
  *(bf16x4*)&Sx[row * 2560 + c1] = pr;
}

// ---------------------------------------------------------------------------
// dual LN: Y = ln(U)*ng+nb (f32) ; Yln = plain_ln(Y) (bf16, ffn_ln folded)
// ---------------------------------------------------------------------------
__global__ void ln_dual_kernel(const float* __restrict__ U,
                               const float* __restrict__ ng, const float* __restrict__ nb,
                               float* __restrict__ Y, bf16_t* __restrict__ Yln) {
  int wave = threadIdx.x >> 6, lane = threadIdx.x & 63;
  long row = (long)blockIdx.x * 4 + wave;
  const float4* xp = (const float4*)(U + row * 512);
  float4 v0 = xp[lane], v1 = xp[64 + lane];
  float s  = v0.x + v0.y + v0.z + v0.w + v1.x + v1.y + v1.z + v1.w;
  float s2 = v0.x*v0.x + v0.y*v0.y + v0.z*v0.z + v0.w*v0.w
           + v1.x*v1.x + v1.y*v1.y + v1.z*v1.z + v1.w*v1.w;
#pragma unroll
  for (int o = 32; o; o >>= 1) { s += __shfl_xor(s, o); s2 += __shfl_xor(s2, o); }
  float mean = s * (1.f / 512.f);
  float var  = s2 * (1.f / 512.f) - mean * mean;
  float rstd = rsqrtf(var + 1e-5f);
  float xs[8] = {v0.x, v0.y, v0.z, v0.w, v1.x, v1.y, v1.z, v1.w};
  int   c0 = lane * 4, c1 = 256 + lane * 4;
  float y[8];
#pragma unroll
  for (int t = 0; t < 4; t++) y[t]     = (xs[t] - mean) * rstd * ng[c0 + t] + nb[c0 + t];
#pragma unroll
  for (int t = 0; t < 4; t++) y[4 + t] = (xs[4 + t] - mean) * rstd * ng[c1 + t] + nb[c1 + t];
  float4 w0 = {y[0], y[1], y[2], y[3]}, w1 = {y[4], y[5], y[6], y[7]};
  float4* yp = (float4*)(Y + row * 512);
  yp[lane] = w0; yp[64 + lane] = w1;
  float t1 = 0.f, t2 = 0.f;
#pragma unroll
  for (int t = 0; t < 8; t++) { t1 += y[t]; t2 += y[t] * y[t]; }
#pragma unroll
  for (int o = 32; o; o >>= 1) { t1 += __shfl_xor(t1, o); t2 += __shfl_xor(t2, o); }
  float mean2 = t1 * (1.f / 512.f);
  float var2  = t2 * (1.f / 512.f) - mean2 * mean2;
  float rstd2 = rsqrtf(var2 + 1e-5f);
  bf16x4 pa;
#pragma unroll
  for (int t = 0; t < 4; t++) pa[t] = (bf16_t)((y[t] - mean2) * rstd2);
  *(bf16x4*)&Yln[row * 512 + c0] = pa;
#pragma unroll
  for (int t = 0; t < 4; t++) pa[t] = (bf16_t)((y[4 + t] - mean2) * rstd2);
  *(bf16x4*)&Yln[row * 512 + c1] = pa;
}

// ---------------------------------------------------------------------------
extern "C" void kernel_launch(void* const* d_in, const int* in_sizes, int n_in,
                              void* d_out, int out_size, void* d_ws, size_t ws_size,
                              hipStream_t stream) {
  const int M = 16384;             // B*K tokens
  const float* slots    = (const float*)d_in[0];
  const float* keep     = (const float*)d_in[1];
  const float* attn     = (const float*)d_in[2];
  const float* pm1_w    = (const float*)d_in[5];
  const float* pm1_b    = (const float*)d_in[6];
  const float* pm2_w    = (const float*)d_in[7];
  const float* pm2_b    = (const float*)d_in[8];
  const float* fwd_ln_g = (const float*)d_in[9];
  const float* fwd_ln_b = (const float*)d_in[10];
  const float* fwd_in_w = (const float*)d_in[11];
  const float* fwd_in_b = (const float*)d_in[12];
  const float* fwd_out_w= (const float*)d_in[13];
  const float* fwd_out_b= (const float*)d_in[14];
  const float* bwd_ln_g = (const float*)d_in[15];
  const float* bwd_ln_b = (const float*)d_in[16];
  const float* bwd_in_w = (const float*)d_in[17];
  const float* bwd_in_b = (const float*)d_in[18];
  const float* bwd_out_w= (const float*)d_in[19];
  const float* bwd_out_b= (const float*)d_in[20];
  const float* merge_w  = (const float*)d_in[21];
  const float* merge_b  = (const float*)d_in[22];
  const float* norm_g   = (const float*)d_in[23];
  const float* norm_b   = (const float*)d_in[24];
  const float* ffn_ln_g = (const float*)d_in[25];
  const float* ffn_ln_b = (const float*)d_in[26];
  const float* ffn1_w   = (const float*)d_in[27];
  const float* ffn1_b   = (const float*)d_in[28];
  const float* ffn2_w   = (const float*)d_in[29];
  const float* ffn2_b   = (const float*)d_in[30];

  char* w = (char*)d_ws;
  size_t off = 0;
  auto alloc = [&](size_t bytes) { size_t r = off; off += (bytes + 255) & ~(size_t)255; return r; };

  bf16_t* pm1t = (bf16_t*)(w + alloc(512 * 256 * 2));
  bf16_t* pm2t = (bf16_t*)(w + alloc(512 * 512 * 2));
  bf16_t *WzT[2], *WgT[2], *ffn1t[2], *ffn2t[2], *merget[2], *foutbf[2], *boutbf[2], *Bcomp[2];
  float  *bias_gated[2], *bias_ffn1[2], *bias_u[2];
  for (int l = 0; l < 2; l++) {
    WzT[l]    = (bf16_t*)(w + alloc(2048 * 512 * 2));
    WgT[l]    = (bf16_t*)(w + alloc(2048 * 512 * 2));
    ffn1t[l]  = (bf16_t*)(w + alloc(2048 * 512 * 2));
    ffn2t[l]  = (bf16_t*)(w + alloc(512 * 2048 * 2));
    merget[l] = (bf16_t*)(w + alloc(512 * 1024 * 2));
    foutbf[l] = (bf16_t*)(w + alloc(1024 * 512 * 2));
    boutbf[l] = (bf16_t*)(w + alloc(1024 * 512 * 2));
    Bcomp[l]  = (bf16_t*)(w + alloc(512 * 2560 * 2));
    bias_gated[l] = (float*)(w + alloc(4096 * 4));
    bias_ffn1[l]  = (float*)(w + alloc(2048 * 4));
    bias_u[l]     = (float*)(w + alloc(512 * 4));
  }
  float*  cent = (float*)(w + alloc((size_t)M * 2 * 4));
  float*  X    = (float*)(w + alloc((size_t)M * 512 * 4));
  float*  Y    = (float*)(w + alloc((size_t)M * 512 * 4));
  float*  U    = (float*)(w + alloc((size_t)M * 512 * 4));
  bf16_t* Xn   = (bf16_t*)(w + alloc((size_t)M * 512 * 2));
  bf16_t* S    = (bf16_t*)(w + alloc((size_t)M * 2560 * 2));
  bf16_t* FF1  = (bf16_t*)(w + alloc((size_t)M * 2048 * 2));
  bf16_t* Yln  = (bf16_t*)(w + alloc((size_t)M * 512 * 2));
  bf16_t* Enc  = (bf16_t*)(w + alloc((size_t)M * 256 * 2));
  bf16_t* P1   = (bf16_t*)(w + alloc((size_t)M * 512 * 2));

  const size_t WSTRIDE = (size_t)512 * 2048;  // per-layer f32 weight stride

  // 1. init bias buffers with their b0 term (one launch)
  CopyArgs ca{};
  int nc = 0, cb = 0;
  auto addC = [&](const float* s, float* dst, int len) {
    ca.d[nc] = {s, dst, cb, len};
    cb += (len + 255) & ~255; nc++;
  };
  for (int l = 0; l < 2; l++) {
    addC(fwd_in_b + l * 2048,        bias_gated[l],        1024);
    addC(bwd_in_b + l * 2048,        bias_gated[l] + 1024, 1024);
    addC(fwd_in_b + l * 2048 + 1024, bias_gated[l] + 2048, 1024);
    addC(bwd_in_b + l * 2048 + 1024, bias_gated[l] + 3072, 1024);
    addC(ffn1_b + l * 2048,          bias_ffn1[l],         2048);
    addC(merge_b + l * 512,          bias_u[l],            512);
  }
  ca.nd = nc;
  init_bias<<<cb / 256, 256, 0, stream>>>(ca);

  // 2. transpose/cast all weights (one launch); gamma folded via rowScale,
  //    beta@W bias terms accumulated via fused atomics
  TransArgs ta{};
  int nt = 0, tb = 0;
  auto addT = [&](const float* s, bf16_t* dst, const float* scale,
                  const float* va, const float* vb, float* accOut,
                  int K, int ncols, int srcLd, int srcColOff, int mode) {
    ta.d[nt] = {s, dst, scale, va, vb, accOut, K, ncols, srcLd, srcColOff, tb, mode};
    tb += (K * ncols) >> 10; nt++;
  };
  addT(pm1_w, pm1t, nullptr, nullptr, nullptr, nullptr, 256, 512, 512, 0, 0);
  addT(pm2_w, pm2t, nullptr, nullptr, nullptr, nullptr, 512, 512, 512, 0, 0);
  for (int l = 0; l < 2; l++) {
    const float* fiw = fwd_in_w + (size_t)l * WSTRIDE;
    const float* biw = bwd_in_w + (size_t)l * WSTRIDE;
    const float* flb = fwd_ln_b + l * 512;
    const float* blb = bwd_ln_b + l * 512;
    addT(fiw, WzT[l],              fwd_ln_g + l * 512, flb, nullptr, bias_gated[l],        512, 1024, 2048, 0,    0);
    addT(biw, WzT[l] + 1024 * 512, bwd_ln_g + l * 512, blb, nullptr, bias_gated[l] + 1024, 512, 1024, 2048, 0,    0);
    addT(fiw, WgT[l],              fwd_ln_g + l * 512, flb, nullptr, bias_gated[l] + 2048, 512, 1024, 2048, 1024, 0);
    addT(biw, WgT[l] + 1024 * 512, bwd_ln_g + l * 512, blb, nullptr, bias_gated[l] + 3072, 512, 1024, 2048, 1024, 0);
    addT(merge_w + (size_t)l * 1024 * 512, merget[l], nullptr,
         fwd_out_b + l * 512, bwd_out_b + l * 512, bias_u[l], 1024, 512, 512, 0, 0);
    addT(ffn1_w + (size_t)l * WSTRIDE, ffn1t[l], ffn_ln_g + l * 512,
         ffn_ln_b + l * 512, nullptr, bias_ffn1[l], 512, 2048, 2048, 0, 0);
    addT(ffn2_w + (size_t)l * WSTRIDE, ffn2t[l], nullptr, nullptr, nullptr, nullptr, 2048, 512, 512, 0, 0);
    addT(fwd_out_w + (size_t)l * 1024 * 512, foutbf[l], nullptr, nullptr, nullptr, nullptr, 1024, 512, 0, 0, 1);
    addT(bwd_out_w + (size_t)l * 1024 * 512, boutbf[l], nullptr, nullptr, nullptr, nullptr, 1024, 512, 0, 0, 1);
  }
  ta.nd = nt;
  transpose_all<<<tb, 256, 0, stream>>>(ta);

  // 3. composite weights: Bcomp[l] rows n (512), cols k (2560):
  //    [0..1023]=(Wf@Mt)^T  [1024..2047]=(Wb@Mb)^T  [2048..2559]=(Mt+Mb)^T
  PrepArgs pa{};
  pa.d[0] = {merget[0],       foutbf[0], Bcomp[0], 0};
  pa.d[1] = {merget[0] + 512, boutbf[0], Bcomp[0], 1024};
  pa.d[2] = {merget[1],       foutbf[1], Bcomp[1], 0};
  pa.d[3] = {merget[1] + 512, boutbf[1], Bcomp[1], 1024};
  gemm_prep_all<<<128, 256, 0, stream>>>(pa);
  build_mtmb<<<2048, 256, 0, stream>>>(merget[0], Bcomp[0], merget[1], Bcomp[1]);

  // 4. centroids (also writes output tail) + positional encoding
  float* outCent = (float*)d_out + (size_t)M * 512;
  centroid_kernel<<<M / 4, 256, 0, stream>>>(attn, cent, outCent);
  enc_kernel<<<(M * 32) / 256, 256, 0, stream>>>(cent, Enc);

  // 5. pos-enc MLP: P1 = gelu(Enc@pm1+b) ; X = slots + P1@pm2 + b
  gemm_mfma<MODE_GELU><<<dim3(4, 128), 256, 0, stream>>>(
      Enc, pm1t, nullptr, pm1_b, nullptr, nullptr, P1, M, 512, 256, 256, 512, 0);
  gemm_mfma<MODE_RES_F><<<dim3(4, 128), 256, 0, stream>>>(
      P1, pm2t, nullptr, pm2_b, slots, nullptr, X, M, 512, 512, 512, 512, 0);

  // 6. layers
  for (int l = 0; l < 2; l++) {
    // Xn = plain_ln(X); S[:,2048:] = bf16(X)
    ln_plain_kernel<<<M / 4, 256, 0, stream>>>(X, Xn, S + 2048);
    // S[:,0:2048] = [silu*sig fwd | silu*sig bwd]  (one dual GEMM, N=2048)
    gemm_mfma<MODE_GATED><<<dim3(16, 128), 256, 0, stream>>>(
        Xn, WzT[l], WgT[l], bias_gated[l], nullptr, nullptr, S,
        M, 2048, 512, 512, 2560, 0);
    // U = X + S @ Bcomp^T + bias_u   (K=2560: fwd-out + bwd-out + merge fused)
    gemm_mfma<MODE_RES_F><<<dim3(4, 128), 256, 0, stream>>>(
        S, Bcomp[l], nullptr, bias_u[l], X, nullptr, U,
        M, 512, 2560, 2560, 512, 0);
    // Y = ln(U)*ng+nb ; Yln = plain_ln(Y)
    ln_dual_kernel<<<M / 4, 256, 0, stream>>>(U, norm_g + l * 512, norm_b + l * 512, Y, Yln);
    // FF1 = gelu(Yln @ ffn1' + b')
    gemm_mfma<MODE_GELU><<<dim3(16, 128), 256, 0, stream>>>(
        Yln, ffn1t[l], nullptr, bias_ffn1[l], nullptr, nullptr, FF1,
        M, 2048, 512, 512, 2048, 0);
    // X = (Y + FF1 @ ffn2 + b) * keep   (last layer writes d_out directly)
    float* Xdst = (l == 1) ? (float*)d_out : X;
    gemm_mfma<MODE_FFN2><<<dim3(4, 128), 256, 0, stream>>>(
        FF1, ffn2t[l], nullptr, ffn2_b + l * 512, Y, keep, Xdst,
        M, 512, 2048, 2048, 512, 0);
  }
}

// Round 6
// 1102.840 us; speedup vs baseline: 1.0384x; 1.0384x over previous
//
#include <hip/hip_runtime.h>

typedef __bf16 bf16_t;
typedef __bf16 bf16x8 __attribute__((ext_vector_type(8)));
typedef __bf16 bf16x4 __attribute__((ext_vector_type(4)));
typedef float  f32x4  __attribute__((ext_vector_type(4)));

#define MODE_GELU   0
#define MODE_GATED  1
#define MODE_RES_F  3
#define MODE_FFN2   4

__device__ __forceinline__ void async16(const void* g, void* l) {
  __builtin_amdgcn_global_load_lds(
      (const __attribute__((address_space(1))) void*)g,
      (__attribute__((address_space(3))) void*)l, 16, 0, 0);
}

// fast transcendental helpers: v_exp_f32 / v_rcp_f32 based, bf16-exact
__device__ __forceinline__ float fast_exp(float x) {
  return __builtin_amdgcn_exp2f(x * 1.44269504088896f);
}
__device__ __forceinline__ float fast_sigmoid(float x) {
  return __builtin_amdgcn_rcpf(1.0f + fast_exp(-x));
}
// gelu via Abramowitz-Stegun 7.1.26 erf approx, |eps| <= 1.5e-7
__device__ __forceinline__ float fast_gelu(float x) {
  float u = fabsf(x) * 0.70710678118f;
  float t = __builtin_amdgcn_rcpf(fmaf(0.3275911f, u, 1.0f));
  float p = t * fmaf(t, fmaf(t, fmaf(t, fmaf(t, 1.061405429f, -1.453152027f),
                                     1.421413741f), -0.284496736f), 0.254829592f);
  float e = __builtin_amdgcn_exp2f(-u * u * 1.44269504088896f);
  float erfu = fmaf(-p, e, 1.0f);
  float s = (x >= 0.f) ? erfu : -erfu;
  return 0.5f * x * (1.0f + s);
}

// ---------------------------------------------------------------------------
// GEMM: C = epilogue(A[M,K](lda) @ B^T[N,K]) ; 128x128 tile, BK=64, 16x16x32
// XCD-aware bijective block swizzle (T1; requires nwg % 8 == 0, all callers).
// ---------------------------------------------------------------------------
template<int MODE>
__launch_bounds__(256, (MODE == MODE_GATED) ? 2 : 3)
__global__ void gemm_mfma(const bf16_t* __restrict__ A,
                          const bf16_t* __restrict__ B1,
                          const bf16_t* __restrict__ B2,
                          const float*  __restrict__ bias,
                          const float*  __restrict__ Xres,
                          const float*  __restrict__ mask,
                          void* __restrict__ Cptr,
                          int M, int N, int K, int lda, int ldC)
{
  constexpr bool DUAL = (MODE == MODE_GATED);
  __shared__ bf16_t sA[128 * 64];
  __shared__ bf16_t sB[128 * 64];
  __shared__ bf16_t sB2[DUAL ? 128 * 64 : 8];

  const int tid  = threadIdx.x;
  const int wave = tid >> 6;
  const int lane = tid & 63;
  const int wm = wave & 1;
  const int wn = wave >> 1;

  // XCD swizzle: consecutive-on-XCD work ids -> contiguous m-panel chunks
  const int nwg = gridDim.x * gridDim.y;
  const int bid = blockIdx.y * gridDim.x + blockIdx.x;
  const int wid = (bid & 7) * (nwg >> 3) + (bid >> 3);
  const long m0 = (long)(wid / gridDim.x) * 128;
  const long n0 = (long)(wid % gridDim.x) * 128;

  f32x4 zero4 = {0.f, 0.f, 0.f, 0.f};
  f32x4 acc[4][4];
  f32x4 acc2[DUAL ? 4 : 1][DUAL ? 4 : 1];
#pragma unroll
  for (int i = 0; i < 4; i++)
#pragma unroll
    for (int j = 0; j < 4; j++) acc[i][j] = zero4;
  if constexpr (DUAL) {
#pragma unroll
    for (int i = 0; i < 4; i++)
#pragma unroll
      for (int j = 0; j < 4; j++) acc2[i][j] = zero4;
  }

  const int q    = lane >> 4;   // 0..3
  const int c16  = lane & 15;
  const int sr   = lane >> 3;   // 0..7
  const int sg   = lane & 7;
  const int stRow = wave * 8 + sr;   // 0..31

  for (long k0 = 0; k0 < K; k0 += 64) {
#pragma unroll
    for (int i = 0; i < 4; i++) {
      int  r     = i * 32 + stRow;
      int  g     = sg ^ (r & 7);
      long gA    = (long)r * lda + k0 + g * 8;
      long gB    = (long)r * K   + k0 + g * 8;
      int  lbase = i * 2048 + wave * 512;   // elements
      async16(A  + m0 * lda + gA, &sA[lbase]);
      async16(B1 + n0 * K   + gB, &sB[lbase]);
      if constexpr (DUAL) async16(B2 + n0 * K + gB, &sB2[lbase]);
    }
    __syncthreads();
#pragma unroll
    for (int kk = 0; kk < 2; kk++) {
      bf16x8 af[4], bfr[4], b2fr[DUAL ? 4 : 1];
#pragma unroll
      for (int i = 0; i < 4; i++) {
        int r = wm * 64 + i * 16 + c16;
        int g = (kk * 4 + q) ^ (r & 7);
        af[i] = *(const bf16x8*)&sA[r * 64 + g * 8];
      }
#pragma unroll
      for (int j = 0; j < 4; j++) {
        int r = wn * 64 + j * 16 + c16;
        int g = (kk * 4 + q) ^ (r & 7);
        bfr[j] = *(const bf16x8*)&sB[r * 64 + g * 8];
        if constexpr (DUAL) b2fr[j] = *(const bf16x8*)&sB2[r * 64 + g * 8];
      }
#pragma unroll
      for (int i = 0; i < 4; i++)
#pragma unroll
        for (int j = 0; j < 4; j++) {
          acc[i][j] = __builtin_amdgcn_mfma_f32_16x16x32_bf16(af[i], bfr[j], acc[i][j], 0, 0, 0);
          if constexpr (DUAL)
            acc2[i][j] = __builtin_amdgcn_mfma_f32_16x16x32_bf16(af[i], b2fr[j], acc2[i][j], 0, 0, 0);
        }
    }
    __syncthreads();
  }

  // epilogue: direct stores. C/D layout col=lane&15, row=(lane>>4)*4+reg
#pragma unroll
  for (int i = 0; i < 4; i++) {
#pragma unroll
    for (int j = 0; j < 4; j++) {
#pragma unroll
      for (int r = 0; r < 4; r++) {
        long m = m0 + wm * 64 + i * 16 + q * 4 + r;
        long n = n0 + wn * 64 + j * 16 + c16;
        float v = acc[i][j][r];
        if constexpr (MODE == MODE_GELU) {
          float x  = v + bias[n];
          ((bf16_t*)Cptr)[m * (long)ldC + n] = (bf16_t)fast_gelu(x);
        } else if constexpr (MODE == MODE_GATED) {
          float z  = v + bias[n];
          float gt = acc2[i][j][r] + bias[N + n];
          float sz = z * fast_sigmoid(z);
          float sg_ = fast_sigmoid(gt);
          ((bf16_t*)Cptr)[m * (long)ldC + n] = (bf16_t)(sz * sg_);
        } else if constexpr (MODE == MODE_RES_F) {
          float x = Xres[m * (long)N + n] + v + bias[n];
          ((float*)Cptr)[m * (long)ldC + n] = x;
        } else {  // MODE_FFN2
          float x = (Xres[m * (long)N + n] + v + bias[n]) * mask[m];
          ((float*)Cptr)[m * (long)ldC + n] = x;
        }
      }
    }
  }
}

// ---------------------------------------------------------------------------
// batched composite-weight GEMM (prep): C[m, coff+n] = A[m,:]@B[n,:], bf16 out
// fixed geometry M=512, N=1024, K=512, lda=1024, ldC=2560; 32 blocks/desc
// ---------------------------------------------------------------------------
struct PrepDesc { const bf16_t* A; const bf16_t* B; bf16_t* C; int coff; };
struct PrepArgs { PrepDesc d[4]; };

__launch_bounds__(256, 3)
__global__ void gemm_prep_all(PrepArgs a) {
  PrepDesc d = a.d[blockIdx.x >> 5];
  const int t = blockIdx.x & 31;
  const long m0 = (long)(t >> 3) * 128;
  const long n0 = (long)(t & 7) * 128;
  const int lda = 1024, K = 512, ldC = 2560;

  __shared__ bf16_t sA[128 * 64];
  __shared__ bf16_t sB[128 * 64];

  const int tid  = threadIdx.x;
  const int wave = tid >> 6;
  const int lane = tid & 63;
  const int wm = wave & 1;
  const int wn = wave >> 1;

  f32x4 zero4 = {0.f, 0.f, 0.f, 0.f};
  f32x4 acc[4][4];
#pragma unroll
  for (int i = 0; i < 4; i++)
#pragma unroll
    for (int j = 0; j < 4; j++) acc[i][j] = zero4;

  const int q    = lane >> 4;
  const int c16  = lane & 15;
  const int sr   = lane >> 3;
  const int sg   = lane & 7;
  const int stRow = wave * 8 + sr;

  for (long k0 = 0; k0 < K; k0 += 64) {
#pragma unroll
    for (int i = 0; i < 4; i++) {
      int  r     = i * 32 + stRow;
      int  g     = sg ^ (r & 7);
      int  lbase = i * 2048 + wave * 512;
      async16(d.A + (m0 + r) * lda + k0 + g * 8, &sA[lbase]);
      async16(d.B + (n0 + r) * K   + k0 + g * 8, &sB[lbase]);
    }
    __syncthreads();
#pragma unroll
    for (int kk = 0; kk < 2; kk++) {
      bf16x8 af[4], bfr[4];
#pragma unroll
      for (int i = 0; i < 4; i++) {
        int r = wm * 64 + i * 16 + c16;
        int g = (kk * 4 + q) ^ (r & 7);
        af[i] = *(const bf16x8*)&sA[r * 64 + g * 8];
      }
#pragma unroll
      for (int j = 0; j < 4; j++) {
        int r = wn * 64 + j * 16 + c16;
        int g = (kk * 4 + q) ^ (r & 7);
        bfr[j] = *(const bf16x8*)&sB[r * 64 + g * 8];
      }
#pragma unroll
      for (int i = 0; i < 4; i++)
#pragma unroll
        for (int j = 0; j < 4; j++)
          acc[i][j] = __builtin_amdgcn_mfma_f32_16x16x32_bf16(af[i], bfr[j], acc[i][j], 0, 0, 0);
    }
    __syncthreads();
  }
#pragma unroll
  for (int i = 0; i < 4; i++)
#pragma unroll
    for (int j = 0; j < 4; j++)
#pragma unroll
      for (int r = 0; r < 4; r++) {
        long m = m0 + wm * 64 + i * 16 + q * 4 + r;
        long n = n0 + wn * 64 + j * 16 + c16;
        d.C[m * ldC + d.coff + n] = (bf16_t)acc[i][j][r];
      }
}

// ---------------------------------------------------------------------------
// transpose/cast all weights, one launch, with FUSED bias-fold accumulation:
// mode 0: f32 src[K, srcLd] cols [srcColOff..+ncols) -> bf16 dst[ncols, K],
//         optional per-row gamma scale; optional accOut[j] += sum_k v[k]*raw
//         (v split va/vb at row 512; atomicAdd, init'd by init_bias)
// mode 1: plain elementwise cast
// ---------------------------------------------------------------------------
struct TransDesc { const float* src; bf16_t* dst; const float* rowScale;
                   const float* accVa; const float* accVb; float* accOut;
                   int K, ncols, srcLd, srcColOff, tileBase, mode; };
struct TransArgs { TransDesc d[24]; int nd; };

__global__ void transpose_all(TransArgs args) {
  __shared__ float tile[32][33];
  __shared__ float red[8][32];
  int bid = blockIdx.x;
  int di = 0;
  while (di + 1 < args.nd && bid >= args.d[di + 1].tileBase) ++di;
  TransDesc d = args.d[di];
  int t = bid - d.tileBase;
  if (d.mode == 1) {
    long idx = (long)t * 1024 + threadIdx.x * 4;
    float4 v = *(const float4*)(d.src + idx);
    bf16x4 o; o[0] = (bf16_t)v.x; o[1] = (bf16_t)v.y; o[2] = (bf16_t)v.z; o[3] = (bf16_t)v.w;
    *(bf16x4*)(d.dst + idx) = o;
    return;
  }
  int tilesX = d.ncols >> 5;
  int ty = t / tilesX, tx = t % tilesX;
  int lx = threadIdx.x & 31, ly = threadIdx.x >> 5;  // 32x8
  int gx = tx * 32 + lx;
  float p = 0.f;
#pragma unroll
  for (int i = 0; i < 32; i += 8) {
    int gy = ty * 32 + ly + i;
    float raw = d.src[(long)gy * d.srcLd + d.srcColOff + gx];
    if (d.accOut) {
      float v = (d.accVb && gy >= 512) ? d.accVb[gy - 512] : d.accVa[gy];
      p += v * raw;
    }
    float sc = d.rowScale ? d.rowScale[gy] : 1.f;
    tile[ly + i][lx] = raw * sc;
  }
  if (d.accOut) red[ly][lx] = p;
  __syncthreads();
  if (d.accOut && ly == 0) {
    float s = 0.f;
#pragma unroll
    for (int r = 0; r < 8; r++) s += red[r][lx];
    atomicAdd(&d.accOut[tx * 32 + lx], s);
  }
  int ox = ty * 32 + lx;  // k
#pragma unroll
  for (int i = 0; i < 32; i += 8) {
    int oy = tx * 32 + ly + i;  // n
    d.dst[(long)oy * d.K + ox] = (bf16_t)tile[lx][ly + i];
  }
}

// init bias buffers with their b0 term (before transpose_all's atomics)
struct CopyDesc { const float* src; float* dst; int base, len; };
struct CopyArgs { CopyDesc d[12]; int nd; };
__global__ void init_bias(CopyArgs a) {
  int i = blockIdx.x * 256 + threadIdx.x;
  int di = 0;
  while (di + 1 < a.nd && i >= a.d[di + 1].base) ++di;
  CopyDesc d = a.d[di];
  int j = i - d.base;
  if (j < d.len) d.dst[j] = d.src[j];
}

// Bcomp cols 2048..2559: (Mt+Mb)^T[n,k] = merget[n,k] + merget[n,512+k]
__global__ void build_mtmb(const bf16_t* __restrict__ mt0, bf16_t* __restrict__ bc0,
                           const bf16_t* __restrict__ mt1, bf16_t* __restrict__ bc1) {
  int idx = blockIdx.x * 256 + threadIdx.x;   // 2 * 512 * 512
  int l = idx >> 18;
  int r = idx & 262143;
  int n = r >> 9, k = r & 511;
  const bf16_t* mt = l ? mt1 : mt0;
  bf16_t* bc = l ? bc1 : bc0;
  float v = (float)mt[n * 1024 + k] + (float)mt[n * 1024 + 512 + k];
  bc[(long)n * 2560 + 2048 + k] = (bf16_t)v;
}

// ---------------------------------------------------------------------------
// fused centroids + positional encoding: one wave per (b,k) row.
// writes outCent (d_out tail) and enc[row, 256] bf16 directly.
// ---------------------------------------------------------------------------
__global__ void centroid_enc_kernel(const float* __restrict__ attn,
                                    float* __restrict__ outCent,
                                    bf16_t* __restrict__ enc) {
  int wave = threadIdx.x >> 6, lane = threadIdx.x & 63;
  long row = (long)blockIdx.x * 4 + wave;
  const float4* ap = (const float4*)(attn + row * 4096);
  float s = 0.f, sx = 0.f, sy = 0.f;
#pragma unroll 4
  for (int t = 0; t < 16; t++) {
    float4 v = ap[t * 64 + lane];
    int n0 = (t * 64 + lane) * 4;
    float col = (float)(n0 & 63);
    float ry  = (float)(n0 >> 6);
    float rs = v.x + v.y + v.z + v.w;
    s  += rs;
    sx += v.x * col + v.y * (col + 1.f) + v.z * (col + 2.f) + v.w * (col + 3.f);
    sy += rs * ry;
  }
#pragma unroll
  for (int o = 32; o; o >>= 1) {
    s += __shfl_down(s, o); sx += __shfl_down(sx, o); sy += __shfl_down(sy, o);
  }
  float cx = 0.f, cy = 0.f;
  if (lane == 0) {
    float denom = s + 1e-8f;
    cx = (sx * (1.f / 63.f)) / denom;
    cy = (sy * (1.f / 63.f)) / denom;
    outCent[row * 2] = cx;  outCent[row * 2 + 1] = cy;
  }
  cx = __shfl(cx, 0);
  cy = __shfl(cy, 0);
  int j = lane & 31, hi = lane >> 5;
  float freq = expf(-(float)j * 0.28782313662425572f);  // 10000^(-j/32)
  float fx = cx * freq * 3.14159f;
  float fy = cy * freq * 3.14159f;
  float fc = 0.1f * freq * 3.14159f;
  bf16_t* e = enc + (long)row * 256;
  if (hi == 0) {
    e[j]       = (bf16_t)sinf(fx);
    e[64 + j]  = (bf16_t)sinf(fy);
    float sc = sinf(fc);
    e[128 + j] = (bf16_t)sc;
    e[192 + j] = (bf16_t)sc;
  } else {
    e[32 + j]  = (bf16_t)cosf(fx);
    e[96 + j]  = (bf16_t)cosf(fy);
    float cc = cosf(fc);
    e[160 + j] = (bf16_t)cc;
    e[224 + j] = (bf16_t)cc;
  }
}

// ---------------------------------------------------------------------------
// plain LN: Xn = (x-mean)*rstd (bf16)  [LN affine folded into weights/bias]
// also writes raw x as bf16 into S cols 2048..2559 (for x@(Mt+Mb) term)
// ---------------------------------------------------------------------------
__global__ void ln_plain_kernel(const float* __restrict__ X,
                                bf16_t* __restrict__ Xn, bf16_t* __restrict__ Sx) {
  int wave = threadIdx.x >> 6, lane = threadIdx.x & 63;
  long row = (long)blockIdx.x * 4 + wave;
  const float4* xp = (const float4*)(X + row * 512);
  float4 v0 = xp[lane], v1 = xp[64 + lane];
  float s  = v0.x + v0.y + v0.z + v0.w + v1.x + v1.y + v1.z + v1.w;
  float s2 = v0.x*v0.x + v0.y*v0.y + v0.z*v0.z + v0.w*v0.w
           + v1.x*v1.x + v1.y*v1.y + v1.z*v1.z + v1.w*v1.w;
#pragma unroll
  for (int o = 32; o; o >>= 1) { s += __shfl_xor(s, o); s2 += __shfl_xor(s2, o); }
  float mean = s * (1.f / 512.f);
  float var  = s2 * (1.f / 512.f) - mean * mean;
  float rstd = rsqrtf(var + 1e-5f);
  float xs[8] = {v0.x, v0.y, v0.z, v0.w, v1.x, v1.y, v1.z, v1.w};
  int   c0 = lane * 4, c1 = 256 + lane * 4;
  bf16x4 pa, pr;
#pragma unroll
  for (int t = 0; t < 4; t++) {
    pa[t] = (bf16_t)((xs[t] - mean) * rstd);
    pr[t] = (bf16_t)xs[t];
  }
  *(bf16x4*)&Xn[row * 512 + c0] = pa;
  *(bf16x4*)&Sx[row * 2560 + c0] = pr;
#pragma unroll
  for (int t = 0; t < 4; t++) {
    pa[t] = (bf16_t)((xs[4 + t] - mean) * rstd);
    pr[t] = (bf16_t)xs[4 + t];
  }
  *(bf16x4*)&Xn[row * 512 + c1] = pa;
  *(bf16x4*)&Sx[row * 2560 + c1] = pr;
}

// ---------------------------------------------------------------------------
// dual LN: Y = ln(U)*ng+nb (f32) ; Yln = plain_ln(Y) (bf16, ffn_ln folded)
// ---------------------------------------------------------------------------
__global__ void ln_dual_kernel(const float* __restrict__ U,
                               const float* __restrict__ ng, const float* __restrict__ nb,
                               float* __restrict__ Y, bf16_t* __restrict__ Yln) {
  int wave = threadIdx.x >> 6, lane = threadIdx.x & 63;
  long row = (long)blockIdx.x * 4 + wave;
  const float4* xp = (const float4*)(U + row * 512);
  float4 v0 = xp[lane], v1 = xp[64 + lane];
  float s  = v0.x + v0.y + v0.z + v0.w + v1.x + v1.y + v1.z + v1.w;
  float s2 = v0.x*v0.x + v0.y*v0.y + v0.z*v0.z + v0.w*v0.w
           + v1.x*v1.x + v1.y*v1.y + v1.z*v1.z + v1.w*v1.w;
#pragma unroll
  for (int o = 32; o; o >>= 1) { s += __shfl_xor(s, o); s2 += __shfl_xor(s2, o); }
  float mean = s * (1.f / 512.f);
  float var  = s2 * (1.f / 512.f) - mean * mean;
  float rstd = rsqrtf(var + 1e-5f);
  float xs[8] = {v0.x, v0.y, v0.z, v0.w, v1.x, v1.y, v1.z, v1.w};
  int   c0 = lane * 4, c1 = 256 + lane * 4;
  float y[8];
#pragma unroll
  for (int t = 0; t < 4; t++) y[t]     = (xs[t] - mean) * rstd * ng[c0 + t] + nb[c0 + t];
#pragma unroll
  for (int t = 0; t < 4; t++) y[4 + t] = (xs[4 + t] - mean) * rstd * ng[c1 + t] + nb[c1 + t];
  float4 w0 = {y[0], y[1], y[2], y[3]}, w1 = {y[4], y[5], y[6], y[7]};
  float4* yp = (float4*)(Y + row * 512);
  yp[lane] = w0; yp[64 + lane] = w1;
  float t1 = 0.f, t2 = 0.f;
#pragma unroll
  for (int t = 0; t < 8; t++) { t1 += y[t]; t2 += y[t] * y[t]; }
#pragma unroll
  for (int o = 32; o; o >>= 1) { t1 += __shfl_xor(t1, o); t2 += __shfl_xor(t2, o); }
  float mean2 = t1 * (1.f / 512.f);
  float var2  = t2 * (1.f / 512.f) - mean2 * mean2;
  float rstd2 = rsqrtf(var2 + 1e-5f);
  bf16x4 pa;
#pragma unroll
  for (int t = 0; t < 4; t++) pa[t] = (bf16_t)((y[t] - mean2) * rstd2);
  *(bf16x4*)&Yln[row * 512 + c0] = pa;
#pragma unroll
  for (int t = 0; t < 4; t++) pa[t] = (bf16_t)((y[4 + t] - mean2) * rstd2);
  *(bf16x4*)&Yln[row * 512 + c1] = pa;
}

// ---------------------------------------------------------------------------
extern "C" void kernel_launch(void* const* d_in, const int* in_sizes, int n_in,
                              void* d_out, int out_size, void* d_ws, size_t ws_size,
                              hipStream_t stream) {
  const int M = 16384;             // B*K tokens
  const float* slots    = (const float*)d_in[0];
  const float* keep     = (const float*)d_in[1];
  const float* attn     = (const float*)d_in[2];
  const float* pm1_w    = (const float*)d_in[5];
  const float* pm1_b    = (const float*)d_in[6];
  const float* pm2_w    = (const float*)d_in[7];
  const float* pm2_b    = (const float*)d_in[8];
  const float* fwd_ln_g = (const float*)d_in[9];
  const float* fwd_ln_b = (const float*)d_in[10];
  const float* fwd_in_w = (const float*)d_in[11];
  const float* fwd_in_b = (const float*)d_in[12];
  const float* fwd_out_w= (const float*)d_in[13];
  const float* fwd_out_b= (const float*)d_in[14];
  const float* bwd_ln_g = (const float*)d_in[15];
  const float* bwd_ln_b = (const float*)d_in[16];
  const float* bwd_in_w = (const float*)d_in[17];
  const float* bwd_in_b = (const float*)d_in[18];
  const float* bwd_out_w= (const float*)d_in[19];
  const float* bwd_out_b= (const float*)d_in[20];
  const float* merge_w  = (const float*)d_in[21];
  const float* merge_b  = (const float*)d_in[22];
  const float* norm_g   = (const float*)d_in[23];
  const float* norm_b   = (const float*)d_in[24];
  const float* ffn_ln_g = (const float*)d_in[25];
  const float* ffn_ln_b = (const float*)d_in[26];
  const float* ffn1_w   = (const float*)d_in[27];
  const float* ffn1_b   = (const float*)d_in[28];
  const float* ffn2_w   = (const float*)d_in[29];
  const float* ffn2_b   = (const float*)d_in[30];

  char* w = (char*)d_ws;
  size_t off = 0;
  auto alloc = [&](size_t bytes) { size_t r = off; off += (bytes + 255) & ~(size_t)255; return r; };

  bf16_t* pm1t = (bf16_t*)(w + alloc(512 * 256 * 2));
  bf16_t* pm2t = (bf16_t*)(w + alloc(512 * 512 * 2));
  bf16_t *WzT[2], *WgT[2], *ffn1t[2], *ffn2t[2], *merget[2], *foutbf[2], *boutbf[2], *Bcomp[2];
  float  *bias_gated[2], *bias_ffn1[2], *bias_u[2];
  for (int l = 0; l < 2; l++) {
    WzT[l]    = (bf16_t*)(w + alloc(2048 * 512 * 2));
    WgT[l]    = (bf16_t*)(w + alloc(2048 * 512 * 2));
    ffn1t[l]  = (bf16_t*)(w + alloc(2048 * 512 * 2));
    ffn2t[l]  = (bf16_t*)(w + alloc(512 * 2048 * 2));
    merget[l] = (bf16_t*)(w + alloc(512 * 1024 * 2));
    foutbf[l] = (bf16_t*)(w + alloc(1024 * 512 * 2));
    boutbf[l] = (bf16_t*)(w + alloc(1024 * 512 * 2));
    Bcomp[l]  = (bf16_t*)(w + alloc(512 * 2560 * 2));
    bias_gated[l] = (float*)(w + alloc(4096 * 4));
    bias_ffn1[l]  = (float*)(w + alloc(2048 * 4));
    bias_u[l]     = (float*)(w + alloc(512 * 4));
  }
  float*  X    = (float*)(w + alloc((size_t)M * 512 * 4));
  float*  Y    = (float*)(w + alloc((size_t)M * 512 * 4));
  float*  U    = (float*)(w + alloc((size_t)M * 512 * 4));
  bf16_t* Xn   = (bf16_t*)(w + alloc((size_t)M * 512 * 2));
  bf16_t* S    = (bf16_t*)(w + alloc((size_t)M * 2560 * 2));
  bf16_t* FF1  = (bf16_t*)(w + alloc((size_t)M * 2048 * 2));
  bf16_t* Yln  = (bf16_t*)(w + alloc((size_t)M * 512 * 2));
  bf16_t* Enc  = (bf16_t*)(w + alloc((size_t)M * 256 * 2));
  bf16_t* P1   = (bf16_t*)(w + alloc((size_t)M * 512 * 2));

  const size_t WSTRIDE = (size_t)512 * 2048;  // per-layer f32 weight stride

  // 1. init bias buffers with their b0 term (one launch)
  CopyArgs ca{};
  int nc = 0, cb = 0;
  auto addC = [&](const float* s, float* dst, int len) {
    ca.d[nc] = {s, dst, cb, len};
    cb += (len + 255) & ~255; nc++;
  };
  for (int l = 0; l < 2; l++) {
    addC(fwd_in_b + l * 2048,        bias_gated[l],        1024);
    addC(bwd_in_b + l * 2048,        bias_gated[l] + 1024, 1024);
    addC(fwd_in_b + l * 2048 + 1024, bias_gated[l] + 2048, 1024);
    addC(bwd_in_b + l * 2048 + 1024, bias_gated[l] + 3072, 1024);
    addC(ffn1_b + l * 2048,          bias_ffn1[l],         2048);
    addC(merge_b + l * 512,          bias_u[l],            512);
  }
  ca.nd = nc;
  init_bias<<<cb / 256, 256, 0, stream>>>(ca);

  // 2. transpose/cast all weights (one launch); gamma folded via rowScale,
  //    beta@W bias terms accumulated via fused atomics
  TransArgs ta{};
  int nt = 0, tb = 0;
  auto addT = [&](const float* s, bf16_t* dst, const float* scale,
                  const float* va, const float* vb, float* accOut,
                  int K, int ncols, int srcLd, int srcColOff, int mode) {
    ta.d[nt] = {s, dst, scale, va, vb, accOut, K, ncols, srcLd, srcColOff, tb, mode};
    tb += (K * ncols) >> 10; nt++;
  };
  addT(pm1_w, pm1t, nullptr, nullptr, nullptr, nullptr, 256, 512, 512, 0, 0);
  addT(pm2_w, pm2t, nullptr, nullptr, nullptr, nullptr, 512, 512, 512, 0, 0);
  for (int l = 0; l < 2; l++) {
    const float* fiw = fwd_in_w + (size_t)l * WSTRIDE;
    const float* biw = bwd_in_w + (size_t)l * WSTRIDE;
    const float* flb = fwd_ln_b + l * 512;
    const float* blb = bwd_ln_b + l * 512;
    addT(fiw, WzT[l],              fwd_ln_g + l * 512, flb, nullptr, bias_gated[l],        512, 1024, 2048, 0,    0);
    addT(biw, WzT[l] + 1024 * 512, bwd_ln_g + l * 512, blb, nullptr, bias_gated[l] + 1024, 512, 1024, 2048, 0,    0);
    addT(fiw, WgT[l],              fwd_ln_g + l * 512, flb, nullptr, bias_gated[l] + 2048, 512, 1024, 2048, 1024, 0);
    addT(biw, WgT[l] + 1024 * 512, bwd_ln_g + l * 512, blb, nullptr, bias_gated[l] + 3072, 512, 1024, 2048, 1024, 0);
    addT(merge_w + (size_t)l * 1024 * 512, merget[l], nullptr,
         fwd_out_b + l * 512, bwd_out_b + l * 512, bias_u[l], 1024, 512, 512, 0, 0);
    addT(ffn1_w + (size_t)l * WSTRIDE, ffn1t[l], ffn_ln_g + l * 512,
         ffn_ln_b + l * 512, nullptr, bias_ffn1[l], 512, 2048, 2048, 0, 0);
    addT(ffn2_w + (size_t)l * WSTRIDE, ffn2t[l], nullptr, nullptr, nullptr, nullptr, 2048, 512, 512, 0, 0);
    addT(fwd_out_w + (size_t)l * 1024 * 512, foutbf[l], nullptr, nullptr, nullptr, nullptr, 1024, 512, 0, 0, 1);
    addT(bwd_out_w + (size_t)l * 1024 * 512, boutbf[l], nullptr, nullptr, nullptr, nullptr, 1024, 512, 0, 0, 1);
  }
  ta.nd = nt;
  transpose_all<<<tb, 256, 0, stream>>>(ta);

  // 3. composite weights: Bcomp[l] rows n (512), cols k (2560):
  //    [0..1023]=(Wf@Mt)^T  [1024..2047]=(Wb@Mb)^T  [2048..2559]=(Mt+Mb)^T
  PrepArgs pa{};
  pa.d[0] = {merget[0],       foutbf[0], Bcomp[0], 0};
  pa.d[1] = {merget[0] + 512, boutbf[0], Bcomp[0], 1024};
  pa.d[2] = {merget[1],       foutbf[1], Bcomp[1], 0};
  pa.d[3] = {merget[1] + 512, boutbf[1], Bcomp[1], 1024};
  gemm_prep_all<<<128, 256, 0, stream>>>(pa);
  build_mtmb<<<2048, 256, 0, stream>>>(merget[0], Bcomp[0], merget[1], Bcomp[1]);

  // 4. fused centroids + positional encoding (writes output tail + Enc)
  float* outCent = (float*)d_out + (size_t)M * 512;
  centroid_enc_kernel<<<M / 4, 256, 0, stream>>>(attn, outCent, Enc);

  // 5. pos-enc MLP: P1 = gelu(Enc@pm1+b) ; X = slots + P1@pm2 + b
  gemm_mfma<MODE_GELU><<<dim3(4, 128), 256, 0, stream>>>(
      Enc, pm1t, nullptr, pm1_b, nullptr, nullptr, P1, M, 512, 256, 256, 512);
  gemm_mfma<MODE_RES_F><<<dim3(4, 128), 256, 0, stream>>>(
      P1, pm2t, nullptr, pm2_b, slots, nullptr, X, M, 512, 512, 512, 512);

  // 6. layers
  for (int l = 0; l < 2; l++) {
    // Xn = plain_ln(X); S[:,2048:] = bf16(X)
    ln_plain_kernel<<<M / 4, 256, 0, stream>>>(X, Xn, S + 2048);
    // S[:,0:2048] = [silu*sig fwd | silu*sig bwd]  (one dual GEMM, N=2048)
    gemm_mfma<MODE_GATED><<<dim3(16, 128), 256, 0, stream>>>(
        Xn, WzT[l], WgT[l], bias_gated[l], nullptr, nullptr, S,
        M, 2048, 512, 512, 2560);
    // U = X + S @ Bcomp^T + bias_u   (K=2560: fwd-out + bwd-out + merge fused)
    gemm_mfma<MODE_RES_F><<<dim3(4, 128), 256, 0, stream>>>(
        S, Bcomp[l], nullptr, bias_u[l], X, nullptr, U,
        M, 512, 2560, 2560, 512);
    // Y = ln(U)*ng+nb ; Yln = plain_ln(Y)
    ln_dual_kernel<<<M / 4, 256, 0, stream>>>(U, norm_g + l * 512, norm_b + l * 512, Y, Yln);
    // FF1 = gelu(Yln @ ffn1' + b')
    gemm_mfma<MODE_GELU><<<dim3(16, 128), 256, 0, stream>>>(
        Yln, ffn1t[l], nullptr, bias_ffn1[l], nullptr, nullptr, FF1,
        M, 2048, 512, 512, 2048);
    // X = (Y + FF1 @ ffn2 + b) * keep   (last layer writes d_out directly)
    float* Xdst = (l == 1) ? (float*)d_out : X;
    gemm_mfma<MODE_FFN2><<<dim3(4, 128), 256, 0, stream>>>(
        FF1, ffn2t[l], nullptr, ffn2_b + l * 512, Y, keep, Xdst,
        M, 512, 2048, 2048, 512);
  }
}